// Round 6
// baseline (300.024 us; speedup 1.0000x reference)
//
#include <hip/hip_runtime.h>

// ---- problem constants ----
#define T_SEQ 2048
#define NB    2
#define NHEAD 16
#define NKV   4
#define HD    128
#define CDIM  2048
#define QKV_W 3072            // 2048 q + 512 k (+ 512 v, routed to Vt instead)
#define MROWS 4096            // B*T

// 1/sqrt(128) * log2(e), folded into q at RoPE time so attention uses exp2 directly
#define QSCALE 0.12752648137154393f

typedef unsigned int  uint;
typedef unsigned short ushort;

typedef __attribute__((ext_vector_type(8))) __bf16 bf16x8;
typedef __attribute__((ext_vector_type(4))) float  floatx4;

#if __has_builtin(__builtin_amdgcn_exp2f)
#define EXP2F(x) __builtin_amdgcn_exp2f(x)
#else
#define EXP2F(x) exp2f(x)
#endif

__device__ __forceinline__ uint bf16rne(float f) {
  uint u = __float_as_uint(f);
  u += 0x7fffu + ((u >> 16) & 1u);
  return u >> 16;
}
__device__ __forceinline__ float bflo(uint w) { return __uint_as_float(w << 16); }
__device__ __forceinline__ float bfhi(uint w) { return __uint_as_float(w & 0xffff0000u); }

__device__ __forceinline__ void block_bar() {
  __builtin_amdgcn_sched_barrier(0);
  __builtin_amdgcn_s_barrier();
  __builtin_amdgcn_sched_barrier(0);
}

// ---- fp32 -> bf16 cast, 2 elems/thread ----
__global__ void cast_f32_bf16x2(const float* __restrict__ in, uint* __restrict__ out, int n2) {
  int i = blockIdx.x * 256 + threadIdx.x;
  if (i < n2) {
    float2 v = ((const float2*)in)[i];
    out[i] = bf16rne(v.x) | (bf16rne(v.y) << 16);
  }
}

// ---- GEMM C[M,N] = A[M,K] * Bt[N,K]^T  (bf16 in, OutT out) ----
// 8-phase-style schedule (T3+T4+T5 port): BM=128 x BN=256, BK=64, 8 waves
// (512 thr), wave tile 64x64 (4x4 acc, same fragment addressing as r4/r5).
// TRIPLE-buffered LDS (144 KiB): stage tile t+2 during tile t -> loads stay
// in flight ACROSS tile boundaries. Exactly ONE vmcnt(6) per K-tile (FIFO:
// 12 outstanding at tile end -> wait to 6 = tile t+1 landed, t+2 in flight);
// epilogue drains 6 -> 0 once. Per K-tile: 2 phases (kk=0/1), each
// {8 ds_read_b128 ; 3 global_load_lds ; bar ; lgkmcnt(0) ; setprio(1) ;
//  16 MFMA ; setprio(0) ; [vmcnt] ; bar}.
// XOR swizzle chunk ^= row&7 on the GLOBAL source (linear LDS dest), inverted
// on ds_read -> measured 0 bank conflicts (r5).
// Columns >= vcol0 are written TRANSPOSED into vt as [(b*512+(col-vcol0))][T].
__device__ __forceinline__ void store_elem(ushort* C, size_t idx, float v) { C[idx] = (ushort)bf16rne(v); }
__device__ __forceinline__ void store_elem(float*  C, size_t idx, float v) { C[idx] = v; }

template <typename OutT>
__global__ __launch_bounds__(512, 1) void gemm_bt(const ushort* __restrict__ A,
                                                  const ushort* __restrict__ Bt,
                                                  OutT* __restrict__ C,
                                                  int M, int N, int K,
                                                  int vcol0, ushort* __restrict__ vt) {
  // LDS (ushort elems): A bufs 3 x 8192 @ 0 | B bufs 3 x 16384 @ 24576
  __shared__ ushort smem[73728];   // 147456 B (<= 160 KiB/CU; 1 block/CU)
  const int tid  = threadIdx.x;
  const int wave = tid >> 6, lane = tid & 63;
  const int quad = lane >> 4, l16 = lane & 15;
  const int wm = wave >> 2, wn = wave & 3;       // wave tile origin (wm*64, wn*64)
  const int mBase = blockIdx.y << 7;             // BM = 128
  const int nBase = blockIdx.x << 8;             // BN = 256
  const int NKT = K >> 6;                        // BK = 64

  floatx4 acc[4][4];
#pragma unroll
  for (int i = 0; i < 4; ++i)
#pragma unroll
    for (int j = 0; j < 4; ++j)
#pragma unroll
      for (int r = 0; r < 4; ++r) acc[i][j][r] = 0.f;

  // ---- staging addressing: per issue 512 thr x 16 B = 64 rows of [64] ----
  // thread row-in-issue = tid>>3, chunk = tid&7; source chunk pre-swizzled
  // by ^ (row&7); LDS dest linear (wave-uniform base + lane*16B).
  const int srow = tid >> 3;                             // 0..63
  const int sc8  = ((tid & 7) ^ (srow & 7)) << 3;        // pre-swizzled col (elems)
  const ushort* gAa = A  + (size_t)(mBase + srow) * K + sc8;   // A rows it*64+
  const ushort* gBa = Bt + (size_t)(nBase + srow) * K + sc8;   // B rows it*64+

#define GLL(gptr, loff)                                                              \
  __builtin_amdgcn_global_load_lds((const __attribute__((address_space(1))) void*)(gptr), \
      (__attribute__((address_space(3))) void*)(smem + (loff) + (wave << 9)), 16, 0, 0)

  // prologue: tile0 -> buf0, tile1 -> buf1 (6 issues each)
  {
    GLL(gAa,                    0);
    GLL(gAa + (size_t)64 * K,   4096);
    GLL(gBa,                    24576);
    GLL(gBa + (size_t)64 * K,   24576 + 4096);
    GLL(gBa + (size_t)128 * K,  24576 + 8192);
    GLL(gBa + (size_t)192 * K,  24576 + 12288);
    GLL(gAa + 64,                   8192);
    GLL(gAa + (size_t)64 * K + 64,  8192 + 4096);
    GLL(gBa + 64,                   40960);
    GLL(gBa + (size_t)64 * K + 64,  40960 + 4096);
    GLL(gBa + (size_t)128 * K + 64, 40960 + 8192);
    GLL(gBa + (size_t)192 * K + 64, 40960 + 12288);
  }
  asm volatile("s_waitcnt vmcnt(6)" ::: "memory");   // tile0 landed, tile1 in flight
  block_bar();

  int cur = 0;
  for (int t = 0; t < NKT; ++t) {
    const int curA = cur * 8192;
    const int curB = 24576 + cur * 16384;
    const int tgt  = (cur == 0) ? 2 : cur - 1;         // (cur+2) % 3
    const int tgtA = tgt * 8192;
    const int tgtB = 24576 + tgt * 16384;
    const int k2   = (t + 2) << 6;
    const bool stg = (t + 2 < NKT);

    // ---------- phase A: kk = 0 ----------
    {
      const int sw = ((quad ^ (l16 & 7)) << 3);
      bf16x8 af[4], bfr[4];
#pragma unroll
      for (int i = 0; i < 4; ++i)
        af[i]  = *(const bf16x8*)&smem[curA + ((wm << 6) + (i << 4) + l16) * 64 + sw];
#pragma unroll
      for (int j = 0; j < 4; ++j)
        bfr[j] = *(const bf16x8*)&smem[curB + ((wn << 6) + (j << 4) + l16) * 64 + sw];
      if (stg) {
        GLL(gAa + k2,                  tgtA);
        GLL(gAa + (size_t)64 * K + k2, tgtA + 4096);
        GLL(gBa + k2,                  tgtB);
      }
      block_bar();
      asm volatile("s_waitcnt lgkmcnt(0)" ::: "memory");
      __builtin_amdgcn_sched_barrier(0);
      __builtin_amdgcn_s_setprio(1);
#pragma unroll
      for (int i = 0; i < 4; ++i)
#pragma unroll
        for (int j = 0; j < 4; ++j)
          acc[i][j] = __builtin_amdgcn_mfma_f32_16x16x32_bf16(af[i], bfr[j], acc[i][j], 0, 0, 0);
      __builtin_amdgcn_s_setprio(0);
      block_bar();
    }

    // ---------- phase B: kk = 1 ----------
    {
      const int sw = (((quad + 4) ^ (l16 & 7)) << 3);
      bf16x8 af[4], bfr[4];
#pragma unroll
      for (int i = 0; i < 4; ++i)
        af[i]  = *(const bf16x8*)&smem[curA + ((wm << 6) + (i << 4) + l16) * 64 + sw];
#pragma unroll
      for (int j = 0; j < 4; ++j)
        bfr[j] = *(const bf16x8*)&smem[curB + ((wn << 6) + (j << 4) + l16) * 64 + sw];
      if (stg) {
        GLL(gBa + (size_t)64 * K + k2,  tgtB + 4096);
        GLL(gBa + (size_t)128 * K + k2, tgtB + 8192);
        GLL(gBa + (size_t)192 * K + k2, tgtB + 12288);
      }
      block_bar();
      asm volatile("s_waitcnt lgkmcnt(0)" ::: "memory");
      __builtin_amdgcn_sched_barrier(0);
      __builtin_amdgcn_s_setprio(1);
#pragma unroll
      for (int i = 0; i < 4; ++i)
#pragma unroll
        for (int j = 0; j < 4; ++j)
          acc[i][j] = __builtin_amdgcn_mfma_f32_16x16x32_bf16(af[i], bfr[j], acc[i][j], 0, 0, 0);
      __builtin_amdgcn_s_setprio(0);
      // counted tile-boundary wait: t+1's 6 loads landed, t+2's 6 stay in flight
      if (t + 2 < NKT) {
        asm volatile("s_waitcnt vmcnt(6)" ::: "memory");
      } else if (t + 1 < NKT) {
        asm volatile("s_waitcnt vmcnt(0)" ::: "memory");   // final drain
      }
      block_bar();
    }
    cur = (cur == 2) ? 0 : cur + 1;
  }
#undef GLL

  // ---- epilogue: per-fragment store (C or transposed-V path) ----
#pragma unroll
  for (int i = 0; i < 4; ++i) {
    const int rowb = mBase + (wm << 6) + (i << 4) + (quad << 2);
#pragma unroll
    for (int j = 0; j < 4; ++j) {
      const int colb = nBase + (wn << 6) + (j << 4);
      const int col  = colb + l16;
      if (colb < vcol0) {
#pragma unroll
        for (int r = 0; r < 4; ++r)
          store_elem(C, (size_t)(rowb + r) * N + col, acc[i][j][r]);
      } else {
        const int vcol = col - vcol0;
        const int bb = rowb >> 11;
        const int t  = rowb & 2047;
        uint2 pw;
        pw.x = bf16rne(acc[i][j][0]) | (bf16rne(acc[i][j][1]) << 16);
        pw.y = bf16rne(acc[i][j][2]) | (bf16rne(acc[i][j][3]) << 16);
        *(uint2*)(vt + (((size_t)(bb << 9) + vcol) << 11) + t) = pw;
      }
    }
  }
}

// ---- RoPE in-place on qkv; q additionally scaled by QSCALE ----
__global__ void rope_kernel(ushort* __restrict__ qkv, const float* __restrict__ fc,
                            const float* __restrict__ fs) {
  int idx  = blockIdx.x * 256 + threadIdx.x;   // exactly B*T*20*64 threads
  int d2   = idx & 63;
  int rest = idx >> 6;
  int hh   = rest % 20;
  int bt   = rest / 20;
  int t    = bt & (T_SEQ - 1);
  float c = fc[(t << 6) + d2];
  float s = fs[(t << 6) + d2];
  int col = (hh < 16) ? ((hh << 7) + (d2 << 1)) : (2048 + ((hh - 16) << 7) + (d2 << 1));
  float m = (hh < 16) ? QSCALE : 1.0f;
  uint* p = (uint*)(qkv + (size_t)bt * QKV_W + col);
  uint w = *p;
  float e = bflo(w), o = bfhi(w);
  float oe = (e * c - o * s) * m;
  float oo = (e * s + o * c) * m;
  *p = bf16rne(oe) | (bf16rne(oo) << 16);
}

// ---- MFMA flash attention: Q-tile 128, key tile 64, EIGHT waves (512 thr) ----
// Grid 256 blocks (1/CU), blocks paired over Q-tiles {x, 15-x}: 34 chunks each.
// Wave-private P + dbuf direct global_load_lds staging -> ONE barrier per chunk.
//   QK: wave (w_s, w_t): S^T = mfma(Kfrag, Qfrag) for s-block 32 x t-block 32.
//   P : wave-private sP slice -> no cross-wave barrier.
//   PV: wave covers its OWN s-slice (k=32) x FULL d (128); O,l linear in s ->
//       the two w_s partials are summed in the epilogue.
//   K/V double-buffered; staged by global_load_lds with pre-swizzled SOURCE
//   (linear LDS dest); the top-of-loop __syncthreads' vmcnt drain is the
//   staging wait (issued a full phase earlier -> hidden).
__global__ __launch_bounds__(512, 2) void attn_mfma(const ushort* __restrict__ qkv,
                                                    const ushort* __restrict__ vtg,
                                                    ushort* __restrict__ y) {
  __shared__ ushort smem[51456];          // 102912 B
  ushort* sP = smem + 32768;
  float*  sOf = (float*)smem;
  ushort* sO  = smem + 33792;
  float*  sLf = (float*)(smem + 51200);

  const int tid  = threadIdx.x;
  const int wave = tid >> 6, lane = tid & 63;
  const int quad = lane >> 4, l16 = lane & 15;
  const int w_s = wave & 1;               // s-block owner (QK rows + PV k-slice)
  const int w_t = wave >> 1;              // t-block (0..3)
  const int h = blockIdx.y, b = blockIdx.z, kh = h >> 2;
  const size_t bT = (size_t)b * T_SEQ;

  union { uint4 u; bf16x8 v; } ones_u;
  ones_u.u = make_uint4(0x3F803F80u, 0x3F803F80u, 0x3F803F80u, 0x3F803F80u);
  const bf16x8 onesf = ones_u.v;

  const int kr  = tid >> 4;
  const int kc8 = tid & 15;
  const ushort* gK = qkv + (bT + kr) * QKV_W + 2048 + kh * HD + ((kc8 ^ (kr & 7)) << 3);
  const int vd  = tid >> 3;
  const int vsc = tid & 7;
  const ushort* gV = vtg + (((size_t)(b << 9) + (kh << 7) + vd) << 11) + ((vsc ^ (vd & 7)) << 3);

#define STAGE_ATTN(cn, bo_)                                                            \
  do {                                                                                 \
    _Pragma("unroll")                                                                  \
    for (int it_ = 0; it_ < 2; ++it_)                                                  \
      __builtin_amdgcn_global_load_lds(                                                \
          (const __attribute__((address_space(1))) void*)(gK + ((size_t)(cn) * 64 + it_ * 32) * QKV_W), \
          (__attribute__((address_space(3))) void*)(smem + (bo_) + (wave << 9) + it_ * 4096), 16, 0, 0); \
    _Pragma("unroll")                                                                  \
    for (int it_ = 0; it_ < 2; ++it_)                                                  \
      __builtin_amdgcn_global_load_lds(                                                \
          (const __attribute__((address_space(1))) void*)(gV + ((size_t)it_ << 17) + (cn) * 64), \
          (__attribute__((address_space(3))) void*)(smem + 16384 + (bo_) + (wave << 9) + it_ * 4096), 16, 0, 0); \
  } while (0)

  for (int half = 0; half < 2; ++half) {
    const int xt = half ? (15 - (int)blockIdx.x) : (int)blockIdx.x;
    const int t0 = xt << 7;
    const int sblk = w_s << 5, tblk = w_t << 5;

    bf16x8 qf[2][4];
#pragma unroll
    for (int tt = 0; tt < 2; ++tt)
#pragma unroll
      for (int kk = 0; kk < 4; ++kk)
        qf[tt][kk] = *(const bf16x8*)(qkv + (bT + t0 + tblk + tt * 16 + l16) * QKV_W +
                                      h * HD + kk * 32 + quad * 8);

    floatx4 oacc[2][8];     // t-tile (2) x full d (8 x 16)
    floatx4 lacc[2];
#pragma unroll
    for (int tt = 0; tt < 2; ++tt) {
#pragma unroll
      for (int r = 0; r < 4; ++r) lacc[tt][r] = 0.f;
#pragma unroll
      for (int dt = 0; dt < 8; ++dt)
#pragma unroll
        for (int r = 0; r < 4; ++r) oacc[tt][dt][r] = 0.f;
    }

    const int nch = (t0 >> 6) + 2;

    STAGE_ATTN(0, 0);       // prologue: chunk 0 -> buf0 (drained by first sync)

    for (int ch = 0; ch < nch; ++ch) {
      __syncthreads();      // buf[ch&1] staged (vmcnt drained); prev reads done
      if (ch + 1 < nch) STAGE_ATTN(ch + 1, ((ch + 1) & 1) << 13);
      const int bo = (ch & 1) << 13;        // 0 / 8192
      const int s0 = ch << 6;

      const bool fullmask = (s0 + sblk) > (t0 + tblk + 31);
      if (!fullmask) {
        floatx4 accS[2][2];
#pragma unroll
        for (int st = 0; st < 2; ++st)
#pragma unroll
          for (int tt = 0; tt < 2; ++tt)
#pragma unroll
            for (int r = 0; r < 4; ++r) accS[st][tt][r] = 0.f;

#pragma unroll
        for (int kk = 0; kk < 4; ++kk) {
          bf16x8 kf0 = *(const bf16x8*)(smem + bo + (sblk + l16) * 128 +
                                        ((((kk << 2) + quad) ^ (l16 & 7)) << 3));
          bf16x8 kf1 = *(const bf16x8*)(smem + bo + (sblk + 16 + l16) * 128 +
                                        ((((kk << 2) + quad) ^ (l16 & 7)) << 3));
#pragma unroll
          for (int tt = 0; tt < 2; ++tt)
            accS[0][tt] = __builtin_amdgcn_mfma_f32_16x16x32_bf16(kf0, qf[tt][kk], accS[0][tt], 0, 0, 0);
#pragma unroll
          for (int tt = 0; tt < 2; ++tt)
            accS[1][tt] = __builtin_amdgcn_mfma_f32_16x16x32_bf16(kf1, qf[tt][kk], accS[1][tt], 0, 0, 0);
        }

        const bool diag = (s0 + sblk + 31) > (t0 + tblk);
#pragma unroll
        for (int st = 0; st < 2; ++st)
#pragma unroll
          for (int tt = 0; tt < 2; ++tt) {
            float p[4];
            if (diag) {
              const int sg = s0 + sblk + st * 16 + quad * 4;
              const int tg = t0 + tblk + tt * 16 + l16;
#pragma unroll
              for (int r = 0; r < 4; ++r)
                p[r] = (sg + r <= tg) ? EXP2F(accS[st][tt][r]) : 0.f;
            } else {
#pragma unroll
              for (int r = 0; r < 4; ++r) p[r] = EXP2F(accS[st][tt][r]);
            }
            uint2 pw;   // truncating bf16 pack (bias cancels in normalization)
            pw.x = (__float_as_uint(p[0]) >> 16) | (__float_as_uint(p[1]) & 0xFFFF0000u);
            pw.y = (__float_as_uint(p[2]) >> 16) | (__float_as_uint(p[3]) & 0xFFFF0000u);
            *(uint2*)(sP + (tblk + tt * 16 + l16) * 72 + sblk + st * 16 + quad * 4) = pw;
          }
        // no barrier: P is wave-private

        bf16x8 pf[2];
#pragma unroll
        for (int tt = 0; tt < 2; ++tt) {
          pf[tt] = *(const bf16x8*)(sP + (tblk + tt * 16 + l16) * 72 + sblk + (quad << 3));
          lacc[tt] = __builtin_amdgcn_mfma_f32_16x16x32_bf16(pf[tt], onesf, lacc[tt], 0, 0, 0);
        }
#pragma unroll
        for (int dt = 0; dt < 8; ++dt) {
          bf16x8 vf = *(const bf16x8*)(smem + 16384 + bo + (dt * 16 + l16) * 64 +
                                       ((((w_s << 2) + quad) ^ (l16 & 7)) << 3));
#pragma unroll
          for (int tt = 0; tt < 2; ++tt)
            oacc[tt][dt] = __builtin_amdgcn_mfma_f32_16x16x32_bf16(pf[tt], vf, oacc[tt][dt], 0, 0, 0);
        }
      }
    }

    // ---- epilogue: combine w_s partials, normalize, coalesced store ----
    __syncthreads();
    if (w_s == 0) {
#pragma unroll
      for (int tt = 0; tt < 2; ++tt) {
#pragma unroll
        for (int dt = 0; dt < 8; ++dt)
#pragma unroll
          for (int r = 0; r < 4; ++r)
            sOf[(tblk + tt * 16 + quad * 4 + r) * 132 + dt * 16 + l16] = oacc[tt][dt][r];
        if (l16 == 0) {
#pragma unroll
          for (int r = 0; r < 4; ++r)
            sLf[tblk + tt * 16 + quad * 4 + r] = lacc[tt][r];
        }
      }
    }
    __syncthreads();
    if (w_s == 1) {
#pragma unroll
      for (int tt = 0; tt < 2; ++tt) {
        float linv[4];
#pragma unroll
        for (int r = 0; r < 4; ++r)
          linv[r] = 1.0f / (sLf[tblk + tt * 16 + quad * 4 + r] + lacc[tt][r]);
#pragma unroll
        for (int dt = 0; dt < 8; ++dt)
#pragma unroll
          for (int r = 0; r < 4; ++r) {
            float v = (sOf[(tblk + tt * 16 + quad * 4 + r) * 132 + dt * 16 + l16] +
                       oacc[tt][dt][r]) * linv[r];
            sO[(tblk + tt * 16 + quad * 4 + r) * 136 + dt * 16 + l16] = (ushort)bf16rne(v);
          }
      }
    }
    __syncthreads();
#pragma unroll
    for (int it = 0; it < 4; ++it) {
      int idx = it * 512 + tid;                  // 0..2047 = 128 rows x 16 chunks
      int rr = idx >> 4, c8 = idx & 15;
      *(uint4*)(y + (bT + t0 + rr) * CDIM + h * HD + c8 * 8) =
          *(const uint4*)(sO + rr * 136 + c8 * 8);
    }
  }
#undef STAGE_ATTN
}

extern "C" void kernel_launch(void* const* d_in, const int* in_sizes, int n_in,
                              void* d_out, int out_size, void* d_ws, size_t ws_size,
                              hipStream_t stream) {
  const float* x    = (const float*)d_in[0];
  const float* fcos = (const float*)d_in[1];
  const float* fsin = (const float*)d_in[2];
  const float* wq   = (const float*)d_in[3];
  const float* wk   = (const float*)d_in[4];
  const float* wv   = (const float*)d_in[5];
  const float* wo   = (const float*)d_in[6];
  float* out = (float*)d_out;

  // workspace carve (bf16 elems); yb aliases xb (xb dead after gemm1)
  ushort* ws    = (ushort*)d_ws;
  ushort* xb    = ws;                          // 4096*2048 = 8,388,608
  ushort* yb    = ws;                          // alias of xb
  ushort* wqkvb = ws    + 8388608;             // 3072*2048 = 6,291,456
  ushort* wob   = wqkvb + 6291456;             // 2048*2048 = 4,194,304
  ushort* qkv   = wob   + 4194304;             // 4096*3072 = 12,582,912 (v cols unused)
  ushort* vtg   = qkv   + 12582912;            // 2*512*2048 = 2,097,152

  // 1) fp32 -> bf16 casts; wq/wk/wv concatenated row-wise into Wqkv (3072 x 2048)
  cast_f32_bf16x2<<<16384, 256, 0, stream>>>(x,  (uint*)xb,    4194304);
  cast_f32_bf16x2<<< 8192, 256, 0, stream>>>(wq, (uint*)wqkvb, 2097152);
  cast_f32_bf16x2<<< 2048, 256, 0, stream>>>(wk, (uint*)(wqkvb + 4194304), 524288);
  cast_f32_bf16x2<<< 2048, 256, 0, stream>>>(wv, (uint*)(wqkvb + 5242880), 524288);
  cast_f32_bf16x2<<< 8192, 256, 0, stream>>>(wo, (uint*)wob,   2097152);

  // 2) qkv = xb @ Wqkv^T ; V columns (>=2560) written transposed into vtg
  //    BM=128 x BN=256, 8 waves, triple-buffered counted-vmcnt pipeline
  gemm_bt<ushort><<<dim3(QKV_W / 256, MROWS / 128), 512, 0, stream>>>(
      xb, wqkvb, qkv, MROWS, QKV_W, CDIM, 2560, vtg);

  // 3) RoPE in place on q (scaled by QSCALE) and k
  rope_kernel<<<20480, 256, 0, stream>>>(qkv, fcos, fsin);

  // 4) MFMA causal GQA attention -> yb (bf16): Q-tile 128, 8 waves, 256 blocks
  attn_mfma<<<dim3(8, NHEAD, NB), 512, 0, stream>>>(qkv, vtg, yb);

  // 5) out = yb @ wo^T (fp32 out); grid 8x32 = 256 blocks = exactly 1/CU
  gemm_bt<float><<<dim3(CDIM / 256, MROWS / 128), 512, 0, stream>>>(
      yb, wob, out, MROWS, CDIM, CDIM, 1 << 30, nullptr);
}

// Round 7
// 281.686 us; speedup vs baseline: 1.0651x; 1.0651x over previous
//
#include <hip/hip_runtime.h>

// ---- problem constants ----
#define T_SEQ 2048
#define NB    2
#define NHEAD 16
#define NKV   4
#define HD    128
#define CDIM  2048
#define QKV_W 3072            // 2048 q + 512 k (+ 512 v, routed to Vt instead)
#define MROWS 4096            // B*T

// 1/sqrt(128) * log2(e), folded into q at RoPE time so attention uses exp2 directly
#define QSCALE 0.12752648137154393f

typedef unsigned int  uint;
typedef unsigned short ushort;

typedef __attribute__((ext_vector_type(8))) __bf16 bf16x8;
typedef __attribute__((ext_vector_type(4))) float  floatx4;

#if __has_builtin(__builtin_amdgcn_exp2f)
#define EXP2F(x) __builtin_amdgcn_exp2f(x)
#else
#define EXP2F(x) exp2f(x)
#endif

__device__ __forceinline__ uint bf16rne(float f) {
  uint u = __float_as_uint(f);
  u += 0x7fffu + ((u >> 16) & 1u);
  return u >> 16;
}
__device__ __forceinline__ float bflo(uint w) { return __uint_as_float(w << 16); }
__device__ __forceinline__ float bfhi(uint w) { return __uint_as_float(w & 0xffff0000u); }

__device__ __forceinline__ void block_bar() {
  __builtin_amdgcn_sched_barrier(0);
  __builtin_amdgcn_s_barrier();
  __builtin_amdgcn_sched_barrier(0);
}

// ---- merged fp32 -> bf16 cast for all 5 inputs (dest regions contiguous) ----
// ws layout (uint units): xb [0,4194304) | wq [4194304,6291456) |
// wk [6291456,6815744) | wv [6815744,7340032) | wo [7340032,9437184)
__global__ void cast_all(const float* __restrict__ x,  const float* __restrict__ wq,
                         const float* __restrict__ wk, const float* __restrict__ wv,
                         const float* __restrict__ wo, uint* __restrict__ out) {
  int i = blockIdx.x * 256 + threadIdx.x;      // grid exactly 36864 * 256
  const float2* src; int off;
  if (i < 4194304)      { src = (const float2*)x;  off = 0; }
  else if (i < 6291456) { src = (const float2*)wq; off = 4194304; }
  else if (i < 6815744) { src = (const float2*)wk; off = 6291456; }
  else if (i < 7340032) { src = (const float2*)wv; off = 6815744; }
  else                  { src = (const float2*)wo; off = 7340032; }
  float2 v = src[i - off];
  out[i] = bf16rne(v.x) | (bf16rne(v.y) << 16);
}

// ---- GEMM C[M,N] = A[M,K] * Bt[N,K]^T  (bf16 in, OutT out) ----
// r5-proven structure: 128x128 tile, BK=64, FOUR waves (256 thr), wave tile
// 64x64 (4x4 acc). Double-buffered LDS 64 KB -> 2 blocks/CU. Counted vmcnt
// (never 0 in steady state). XOR swizzle chunk ^= row&7 on the GLOBAL source,
// inverted on ds_read (measured 0 bank conflicts, r5).
// ROPE=true (gemm1): columns < 2560 get RoPE applied in the epilogue via
// __shfl_xor(v,1) pairing (even lane -> oe, odd lane -> oo), q cols scaled by
// QSCALE; rotation on f32 accumulators, single bf16 round at the end.
// Columns >= vcol0 are written TRANSPOSED into vt as [(b*512+(col-vcol0))][T].
__device__ __forceinline__ void store_elem(ushort* C, size_t idx, float v) { C[idx] = (ushort)bf16rne(v); }
__device__ __forceinline__ void store_elem(float*  C, size_t idx, float v) { C[idx] = v; }

template <typename OutT, bool ROPE>
__global__ __launch_bounds__(256, 2) void gemm_bt(const ushort* __restrict__ A,
                                                  const ushort* __restrict__ Bt,
                                                  OutT* __restrict__ C,
                                                  int M, int N, int K,
                                                  int vcol0, ushort* __restrict__ vt,
                                                  const float* __restrict__ fc,
                                                  const float* __restrict__ fs) {
  // LDS layout (ushort elems): A buf0 [0,8192) | A buf1 [8192,16384)
  //                            B buf0 [16384,24576) | B buf1 [24576,32768)
  __shared__ ushort smem[32768];   // 65536 B
  const int tid  = threadIdx.x;
  const int wave = tid >> 6, lane = tid & 63;
  const int quad = lane >> 4, l16 = lane & 15;
  const int wm = wave >> 1, wn = wave & 1;       // wave tile origin (wm*64, wn*64)
  const int mBase = blockIdx.y << 7;             // BM = 128
  const int nBase = blockIdx.x << 7;             // BN = 128
  const int NKT = K >> 6;                        // BK = 64

  floatx4 acc[4][4];
#pragma unroll
  for (int i = 0; i < 4; ++i)
#pragma unroll
    for (int j = 0; j < 4; ++j)
#pragma unroll
      for (int r = 0; r < 4; ++r) acc[i][j][r] = 0.f;

  // ---- staging addressing (8 global_load_lds / thread / K-tile) ----
  const int srow = tid >> 3;                             // 0..31
  const int sc8  = ((tid & 7) ^ (srow & 7)) << 3;        // pre-swizzled col (elems)
  const ushort* gA = A  + (size_t)(mBase + srow) * K + sc8;
  const ushort* gB = Bt + (size_t)(nBase + srow) * K + sc8;
  ushort* ldsA = smem + (wave << 9);                     // wave-uniform dest bases
  ushort* ldsB = smem + 16384 + (wave << 9);

#define STAGE(k0, bsel)                                                               \
  do {                                                                                \
    _Pragma("unroll")                                                                 \
    for (int it_ = 0; it_ < 4; ++it_)                                                 \
      __builtin_amdgcn_global_load_lds(                                               \
          (const __attribute__((address_space(1))) void*)(gA + (size_t)it_ * 32 * K + (k0)), \
          (__attribute__((address_space(3))) void*)(ldsA + (bsel) + it_ * 2048), 16, 0, 0);  \
    _Pragma("unroll")                                                                 \
    for (int it_ = 0; it_ < 4; ++it_)                                                 \
      __builtin_amdgcn_global_load_lds(                                               \
          (const __attribute__((address_space(1))) void*)(gB + (size_t)it_ * 32 * K + (k0)), \
          (__attribute__((address_space(3))) void*)(ldsB + (bsel) + it_ * 2048), 16, 0, 0);  \
  } while (0)

  // ---- fragment read bases (reads invert the staging swizzle) ----
  const int aro = ((wm << 6) + l16) * 64;            // + bsel
  const int bro = 16384 + ((wn << 6) + l16) * 64;    // + bsel
  const int sw0 = ((quad       ^ (l16 & 7)) << 3);   // kk=0: chunks 0..3
  const int sw1 = (((quad + 4) ^ (l16 & 7)) << 3);   // kk=1: chunks 4..7

  // prologue: tiles 0 -> buf0, 1 -> buf1; wait tile0 (leave tile1's 8 in flight)
  STAGE(0, 0);
  STAGE(64, 8192);
  asm volatile("s_waitcnt vmcnt(8)" ::: "memory");
  block_bar();

  for (int t = 0; t < NKT; ++t) {
    const int bsel = (t & 1) << 13;                  // 0 / 8192
#pragma unroll
    for (int kk = 0; kk < 2; ++kk) {
      const int sw = kk ? sw1 : sw0;
      bf16x8 bfrag[4];
#pragma unroll
      for (int j = 0; j < 4; ++j)
        bfrag[j] = *(const bf16x8*)&smem[bro + bsel + j * 1024 + sw];
#pragma unroll
      for (int i = 0; i < 4; ++i) {
        bf16x8 ai = *(const bf16x8*)&smem[aro + bsel + i * 1024 + sw];
#pragma unroll
        for (int j = 0; j < 4; ++j)
          acc[i][j] = __builtin_amdgcn_mfma_f32_16x16x32_bf16(ai, bfrag[j], acc[i][j], 0, 0, 0);
      }
    }
    asm volatile("s_waitcnt lgkmcnt(0)" ::: "memory");
    block_bar();                      // all waves done reading buf[t&1]
    if (t + 2 < NKT) {
      STAGE((t + 2) << 6, bsel);      // refill the buffer just consumed
      asm volatile("s_waitcnt vmcnt(8)" ::: "memory");   // tile t+1 landed
      block_bar();
    } else if (t + 1 < NKT) {
      asm volatile("s_waitcnt vmcnt(0)" ::: "memory");   // final prefetch drain
      block_bar();
    }
  }
#undef STAGE

  // ---- epilogue: per-fragment store (C [+RoPE] or transposed-V path) ----
#pragma unroll
  for (int i = 0; i < 4; ++i) {
    const int rowb = mBase + (wm << 6) + (i << 4) + (quad << 2);
#pragma unroll
    for (int j = 0; j < 4; ++j) {
      const int colb = nBase + (wn << 6) + (j << 4);
      const int col  = colb + l16;
      if (colb < vcol0) {
        if constexpr (ROPE) {
          // q (<2048): rotate + QSCALE; k (2048..2559): rotate.
          const float m  = (colb < 2048) ? QSCALE : 1.0f;
          const int  d2  = ((colb & 127) + l16) >> 1;
          const bool odd = (l16 & 1);
#pragma unroll
          for (int r = 0; r < 4; ++r) {
            const int trow = (rowb + r) & (T_SEQ - 1);
            float c = fc[(trow << 6) + d2];
            float s = fs[(trow << 6) + d2];
            float v = acc[i][j][r];
            float p = __shfl_xor(v, 1);
            float e = odd ? p : v;
            float o = odd ? v : p;
            float outv = (odd ? (e * s + o * c) : (e * c - o * s)) * m;
            C[(size_t)(rowb + r) * N + col] = (ushort)bf16rne(outv);
          }
        } else {
#pragma unroll
          for (int r = 0; r < 4; ++r)
            store_elem(C, (size_t)(rowb + r) * N + col, acc[i][j][r]);
        }
      } else {
        const int vcol = col - vcol0;
        const int bb = rowb >> 11;
        const int t  = rowb & 2047;
        uint2 pw;
        pw.x = bf16rne(acc[i][j][0]) | (bf16rne(acc[i][j][1]) << 16);
        pw.y = bf16rne(acc[i][j][2]) | (bf16rne(acc[i][j][3]) << 16);
        *(uint2*)(vt + (((size_t)(bb << 9) + vcol) << 11) + t) = pw;
      }
    }
  }
}

// ---- MFMA flash attention: Q-tile 128, key tile 64, EIGHT waves (512 thr) ----
// Grid 256 blocks (1/CU), blocks paired over Q-tiles {x, 15-x}: 34 chunks each.
// Wave-private P + dbuf direct global_load_lds staging -> ONE barrier per chunk.
//   QK: wave (w_s, w_t): S^T = mfma(Kfrag, Qfrag) for s-block 32 x t-block 32.
//   P : wave-private sP slice -> no cross-wave barrier.
//   PV: wave covers its OWN s-slice (k=32) x FULL d (128); O,l linear in s ->
//       the two w_s partials are summed in the epilogue.
//   K/V double-buffered; staged by global_load_lds with pre-swizzled SOURCE
//   (linear LDS dest); the top-of-loop __syncthreads' vmcnt drain is the
//   staging wait (issued a full phase earlier -> hidden).
__global__ __launch_bounds__(512, 2) void attn_mfma(const ushort* __restrict__ qkv,
                                                    const ushort* __restrict__ vtg,
                                                    ushort* __restrict__ y) {
  __shared__ ushort smem[51456];          // 102912 B
  ushort* sP = smem + 32768;
  float*  sOf = (float*)smem;
  ushort* sO  = smem + 33792;
  float*  sLf = (float*)(smem + 51200);

  const int tid  = threadIdx.x;
  const int wave = tid >> 6, lane = tid & 63;
  const int quad = lane >> 4, l16 = lane & 15;
  const int w_s = wave & 1;               // s-block owner (QK rows + PV k-slice)
  const int w_t = wave >> 1;              // t-block (0..3)
  const int h = blockIdx.y, b = blockIdx.z, kh = h >> 2;
  const size_t bT = (size_t)b * T_SEQ;

  union { uint4 u; bf16x8 v; } ones_u;
  ones_u.u = make_uint4(0x3F803F80u, 0x3F803F80u, 0x3F803F80u, 0x3F803F80u);
  const bf16x8 onesf = ones_u.v;

  const int kr  = tid >> 4;
  const int kc8 = tid & 15;
  const ushort* gK = qkv + (bT + kr) * QKV_W + 2048 + kh * HD + ((kc8 ^ (kr & 7)) << 3);
  const int vd  = tid >> 3;
  const int vsc = tid & 7;
  const ushort* gV = vtg + (((size_t)(b << 9) + (kh << 7) + vd) << 11) + ((vsc ^ (vd & 7)) << 3);

#define STAGE_ATTN(cn, bo_)                                                            \
  do {                                                                                 \
    _Pragma("unroll")                                                                  \
    for (int it_ = 0; it_ < 2; ++it_)                                                  \
      __builtin_amdgcn_global_load_lds(                                                \
          (const __attribute__((address_space(1))) void*)(gK + ((size_t)(cn) * 64 + it_ * 32) * QKV_W), \
          (__attribute__((address_space(3))) void*)(smem + (bo_) + (wave << 9) + it_ * 4096), 16, 0, 0); \
    _Pragma("unroll")                                                                  \
    for (int it_ = 0; it_ < 2; ++it_)                                                  \
      __builtin_amdgcn_global_load_lds(                                                \
          (const __attribute__((address_space(1))) void*)(gV + ((size_t)it_ << 17) + (cn) * 64), \
          (__attribute__((address_space(3))) void*)(smem + 16384 + (bo_) + (wave << 9) + it_ * 4096), 16, 0, 0); \
  } while (0)

  for (int half = 0; half < 2; ++half) {
    const int xt = half ? (15 - (int)blockIdx.x) : (int)blockIdx.x;
    const int t0 = xt << 7;
    const int sblk = w_s << 5, tblk = w_t << 5;

    bf16x8 qf[2][4];
#pragma unroll
    for (int tt = 0; tt < 2; ++tt)
#pragma unroll
      for (int kk = 0; kk < 4; ++kk)
        qf[tt][kk] = *(const bf16x8*)(qkv + (bT + t0 + tblk + tt * 16 + l16) * QKV_W +
                                      h * HD + kk * 32 + quad * 8);

    floatx4 oacc[2][8];     // t-tile (2) x full d (8 x 16)
    floatx4 lacc[2];
#pragma unroll
    for (int tt = 0; tt < 2; ++tt) {
#pragma unroll
      for (int r = 0; r < 4; ++r) lacc[tt][r] = 0.f;
#pragma unroll
      for (int dt = 0; dt < 8; ++dt)
#pragma unroll
        for (int r = 0; r < 4; ++r) oacc[tt][dt][r] = 0.f;
    }

    const int nch = (t0 >> 6) + 2;

    STAGE_ATTN(0, 0);       // prologue: chunk 0 -> buf0 (drained by first sync)

    for (int ch = 0; ch < nch; ++ch) {
      __syncthreads();      // buf[ch&1] staged (vmcnt drained); prev reads done
      if (ch + 1 < nch) STAGE_ATTN(ch + 1, ((ch + 1) & 1) << 13);
      const int bo = (ch & 1) << 13;        // 0 / 8192
      const int s0 = ch << 6;

      const bool fullmask = (s0 + sblk) > (t0 + tblk + 31);
      if (!fullmask) {
        floatx4 accS[2][2];
#pragma unroll
        for (int st = 0; st < 2; ++st)
#pragma unroll
          for (int tt = 0; tt < 2; ++tt)
#pragma unroll
            for (int r = 0; r < 4; ++r) accS[st][tt][r] = 0.f;

#pragma unroll
        for (int kk = 0; kk < 4; ++kk) {
          bf16x8 kf0 = *(const bf16x8*)(smem + bo + (sblk + l16) * 128 +
                                        ((((kk << 2) + quad) ^ (l16 & 7)) << 3));
          bf16x8 kf1 = *(const bf16x8*)(smem + bo + (sblk + 16 + l16) * 128 +
                                        ((((kk << 2) + quad) ^ (l16 & 7)) << 3));
#pragma unroll
          for (int tt = 0; tt < 2; ++tt)
            accS[0][tt] = __builtin_amdgcn_mfma_f32_16x16x32_bf16(kf0, qf[tt][kk], accS[0][tt], 0, 0, 0);
#pragma unroll
          for (int tt = 0; tt < 2; ++tt)
            accS[1][tt] = __builtin_amdgcn_mfma_f32_16x16x32_bf16(kf1, qf[tt][kk], accS[1][tt], 0, 0, 0);
        }

        const bool diag = (s0 + sblk + 31) > (t0 + tblk);
#pragma unroll
        for (int st = 0; st < 2; ++st)
#pragma unroll
          for (int tt = 0; tt < 2; ++tt) {
            float p[4];
            if (diag) {
              const int sg = s0 + sblk + st * 16 + quad * 4;
              const int tg = t0 + tblk + tt * 16 + l16;
#pragma unroll
              for (int r = 0; r < 4; ++r)
                p[r] = (sg + r <= tg) ? EXP2F(accS[st][tt][r]) : 0.f;
            } else {
#pragma unroll
              for (int r = 0; r < 4; ++r) p[r] = EXP2F(accS[st][tt][r]);
            }
            uint2 pw;   // truncating bf16 pack (bias cancels in normalization)
            pw.x = (__float_as_uint(p[0]) >> 16) | (__float_as_uint(p[1]) & 0xFFFF0000u);
            pw.y = (__float_as_uint(p[2]) >> 16) | (__float_as_uint(p[3]) & 0xFFFF0000u);
            *(uint2*)(sP + (tblk + tt * 16 + l16) * 72 + sblk + st * 16 + quad * 4) = pw;
          }
        // no barrier: P is wave-private

        bf16x8 pf[2];
#pragma unroll
        for (int tt = 0; tt < 2; ++tt) {
          pf[tt] = *(const bf16x8*)(sP + (tblk + tt * 16 + l16) * 72 + sblk + (quad << 3));
          lacc[tt] = __builtin_amdgcn_mfma_f32_16x16x32_bf16(pf[tt], onesf, lacc[tt], 0, 0, 0);
        }
#pragma unroll
        for (int dt = 0; dt < 8; ++dt) {
          bf16x8 vf = *(const bf16x8*)(smem + 16384 + bo + (dt * 16 + l16) * 64 +
                                       ((((w_s << 2) + quad) ^ (l16 & 7)) << 3));
#pragma unroll
          for (int tt = 0; tt < 2; ++tt)
            oacc[tt][dt] = __builtin_amdgcn_mfma_f32_16x16x32_bf16(pf[tt], vf, oacc[tt][dt], 0, 0, 0);
        }
      }
    }

    // ---- epilogue: combine w_s partials, normalize, coalesced store ----
    __syncthreads();
    if (w_s == 0) {
#pragma unroll
      for (int tt = 0; tt < 2; ++tt) {
#pragma unroll
        for (int dt = 0; dt < 8; ++dt)
#pragma unroll
          for (int r = 0; r < 4; ++r)
            sOf[(tblk + tt * 16 + quad * 4 + r) * 132 + dt * 16 + l16] = oacc[tt][dt][r];
        if (l16 == 0) {
#pragma unroll
          for (int r = 0; r < 4; ++r)
            sLf[tblk + tt * 16 + quad * 4 + r] = lacc[tt][r];
        }
      }
    }
    __syncthreads();
    if (w_s == 1) {
#pragma unroll
      for (int tt = 0; tt < 2; ++tt) {
        float linv[4];
#pragma unroll
        for (int r = 0; r < 4; ++r)
          linv[r] = 1.0f / (sLf[tblk + tt * 16 + quad * 4 + r] + lacc[tt][r]);
#pragma unroll
        for (int dt = 0; dt < 8; ++dt)
#pragma unroll
          for (int r = 0; r < 4; ++r) {
            float v = (sOf[(tblk + tt * 16 + quad * 4 + r) * 132 + dt * 16 + l16] +
                       oacc[tt][dt][r]) * linv[r];
            sO[(tblk + tt * 16 + quad * 4 + r) * 136 + dt * 16 + l16] = (ushort)bf16rne(v);
          }
      }
    }
    __syncthreads();
#pragma unroll
    for (int it = 0; it < 4; ++it) {
      int idx = it * 512 + tid;                  // 0..2047 = 128 rows x 16 chunks
      int rr = idx >> 4, c8 = idx & 15;
      *(uint4*)(y + (bT + t0 + rr) * CDIM + h * HD + c8 * 8) =
          *(const uint4*)(sO + rr * 136 + c8 * 8);
    }
  }
#undef STAGE_ATTN
}

extern "C" void kernel_launch(void* const* d_in, const int* in_sizes, int n_in,
                              void* d_out, int out_size, void* d_ws, size_t ws_size,
                              hipStream_t stream) {
  const float* x    = (const float*)d_in[0];
  const float* fcos = (const float*)d_in[1];
  const float* fsin = (const float*)d_in[2];
  const float* wq   = (const float*)d_in[3];
  const float* wk   = (const float*)d_in[4];
  const float* wv   = (const float*)d_in[5];
  const float* wo   = (const float*)d_in[6];
  float* out = (float*)d_out;

  // workspace carve (bf16 elems); yb aliases xb (xb dead after gemm1)
  ushort* ws    = (ushort*)d_ws;
  ushort* xb    = ws;                          // 4096*2048 = 8,388,608
  ushort* yb    = ws;                          // alias of xb
  ushort* wqkvb = ws    + 8388608;             // 3072*2048 = 6,291,456
  ushort* wob   = wqkvb + 6291456;             // 2048*2048 = 4,194,304
  ushort* qkv   = wob   + 4194304;             // 4096*3072 = 12,582,912 (v cols unused)
  ushort* vtg   = qkv   + 12582912;            // 2*512*2048 = 2,097,152

  // 1) single merged fp32 -> bf16 cast (xb | wqkvb(q,k,v) | wob contiguous)
  cast_all<<<36864, 256, 0, stream>>>(x, wq, wk, wv, wo, (uint*)ws);

  // 2) qkv = xb @ Wqkv^T with RoPE fused into the epilogue (q scaled by QSCALE);
  //    V columns (>=2560) written transposed into vtg
  gemm_bt<ushort, true><<<dim3(QKV_W / 128, MROWS / 128), 256, 0, stream>>>(
      xb, wqkvb, qkv, MROWS, QKV_W, CDIM, 2560, vtg, fcos, fsin);

  // 3) MFMA causal GQA attention -> yb (bf16): Q-tile 128, 8 waves, 256 blocks
  attn_mfma<<<dim3(8, NHEAD, NB), 512, 0, stream>>>(qkv, vtg, yb);

  // 4) out = yb @ wo^T (fp32 out)
  gemm_bt<float, false><<<dim3(CDIM / 128, MROWS / 128), 256, 0, stream>>>(
      yb, wob, out, MROWS, CDIM, CDIM, 1 << 30, nullptr, nullptr, nullptr);
}

// Round 8
// 278.217 us; speedup vs baseline: 1.0784x; 1.0125x over previous
//
#include <hip/hip_runtime.h>

// ---- problem constants ----
#define T_SEQ 2048
#define NB    2
#define NHEAD 16
#define NKV   4
#define HD    128
#define CDIM  2048
#define QKV_W 3072            // 2048 q + 512 k (+ 512 v, routed to Vt instead)
#define MROWS 4096            // B*T

// 1/sqrt(128) * log2(e); applied to q in-register inside attn (with RoPE)
#define QSCALE 0.12752648137154393f

typedef unsigned int  uint;
typedef unsigned short ushort;

typedef __attribute__((ext_vector_type(8))) __bf16 bf16x8;
typedef __attribute__((ext_vector_type(4))) float  floatx4;

#if __has_builtin(__builtin_amdgcn_exp2f)
#define EXP2F(x) __builtin_amdgcn_exp2f(x)
#else
#define EXP2F(x) exp2f(x)
#endif

__device__ __forceinline__ uint bf16rne(float f) {
  uint u = __float_as_uint(f);
  u += 0x7fffu + ((u >> 16) & 1u);
  return u >> 16;
}
__device__ __forceinline__ float bflo(uint w) { return __uint_as_float(w << 16); }
__device__ __forceinline__ float bfhi(uint w) { return __uint_as_float(w & 0xffff0000u); }

__device__ __forceinline__ void block_bar() {
  __builtin_amdgcn_sched_barrier(0);
  __builtin_amdgcn_s_barrier();
  __builtin_amdgcn_sched_barrier(0);
}

// ---- merged fp32 -> bf16 cast for all 5 inputs (dest regions contiguous) ----
// ws layout (uint units): xb [0,4194304) | wq [4194304,6291456) |
// wk [6291456,6815744) | wv [6815744,7340032) | wo [7340032,9437184)
__global__ void cast_all(const float* __restrict__ x,  const float* __restrict__ wq,
                         const float* __restrict__ wk, const float* __restrict__ wv,
                         const float* __restrict__ wo, uint* __restrict__ out) {
  int i = blockIdx.x * 256 + threadIdx.x;      // grid exactly 36864 * 256
  const float2* src; int off;
  if (i < 4194304)      { src = (const float2*)x;  off = 0; }
  else if (i < 6291456) { src = (const float2*)wq; off = 4194304; }
  else if (i < 6815744) { src = (const float2*)wk; off = 6291456; }
  else if (i < 7340032) { src = (const float2*)wv; off = 6815744; }
  else                  { src = (const float2*)wo; off = 7340032; }
  float2 v = src[i - off];
  out[i] = bf16rne(v.x) | (bf16rne(v.y) << 16);
}

// ---- GEMM C[M,N] = A[M,K] * Bt[N,K]^T  (bf16 in, OutT out) ----
// r5-proven structure (byte-identical body): 128x128 tile, BK=64, FOUR waves
// (256 thr), wave tile 64x64 (4x4 acc). Double-buffered LDS 64 KB -> 2
// blocks/CU. Counted vmcnt (never 0 in steady state). XOR swizzle
// chunk ^= row&7 on the GLOBAL source, inverted on ds_read (0 conflicts, r5).
// Columns >= vcol0 are written TRANSPOSED into vt as [(b*512+(col-vcol0))][T].
__device__ __forceinline__ void store_elem(ushort* C, size_t idx, float v) { C[idx] = (ushort)bf16rne(v); }
__device__ __forceinline__ void store_elem(float*  C, size_t idx, float v) { C[idx] = v; }

template <typename OutT>
__global__ __launch_bounds__(256, 2) void gemm_bt(const ushort* __restrict__ A,
                                                  const ushort* __restrict__ Bt,
                                                  OutT* __restrict__ C,
                                                  int M, int N, int K,
                                                  int vcol0, ushort* __restrict__ vt) {
  // LDS layout (ushort elems): A buf0 [0,8192) | A buf1 [8192,16384)
  //                            B buf0 [16384,24576) | B buf1 [24576,32768)
  __shared__ ushort smem[32768];   // 65536 B
  const int tid  = threadIdx.x;
  const int wave = tid >> 6, lane = tid & 63;
  const int quad = lane >> 4, l16 = lane & 15;
  const int wm = wave >> 1, wn = wave & 1;       // wave tile origin (wm*64, wn*64)
  const int mBase = blockIdx.y << 7;             // BM = 128
  const int nBase = blockIdx.x << 7;             // BN = 128
  const int NKT = K >> 6;                        // BK = 64

  floatx4 acc[4][4];
#pragma unroll
  for (int i = 0; i < 4; ++i)
#pragma unroll
    for (int j = 0; j < 4; ++j)
#pragma unroll
      for (int r = 0; r < 4; ++r) acc[i][j][r] = 0.f;

  // ---- staging addressing (8 global_load_lds / thread / K-tile) ----
  const int srow = tid >> 3;                             // 0..31
  const int sc8  = ((tid & 7) ^ (srow & 7)) << 3;        // pre-swizzled col (elems)
  const ushort* gA = A  + (size_t)(mBase + srow) * K + sc8;
  const ushort* gB = Bt + (size_t)(nBase + srow) * K + sc8;
  ushort* ldsA = smem + (wave << 9);                     // wave-uniform dest bases
  ushort* ldsB = smem + 16384 + (wave << 9);

#define STAGE(k0, bsel)                                                               \
  do {                                                                                \
    _Pragma("unroll")                                                                 \
    for (int it_ = 0; it_ < 4; ++it_)                                                 \
      __builtin_amdgcn_global_load_lds(                                               \
          (const __attribute__((address_space(1))) void*)(gA + (size_t)it_ * 32 * K + (k0)), \
          (__attribute__((address_space(3))) void*)(ldsA + (bsel) + it_ * 2048), 16, 0, 0);  \
    _Pragma("unroll")                                                                 \
    for (int it_ = 0; it_ < 4; ++it_)                                                 \
      __builtin_amdgcn_global_load_lds(                                               \
          (const __attribute__((address_space(1))) void*)(gB + (size_t)it_ * 32 * K + (k0)), \
          (__attribute__((address_space(3))) void*)(ldsB + (bsel) + it_ * 2048), 16, 0, 0);  \
  } while (0)

  // ---- fragment read bases (reads invert the staging swizzle) ----
  const int aro = ((wm << 6) + l16) * 64;            // + bsel
  const int bro = 16384 + ((wn << 6) + l16) * 64;    // + bsel
  const int sw0 = ((quad       ^ (l16 & 7)) << 3);   // kk=0: chunks 0..3
  const int sw1 = (((quad + 4) ^ (l16 & 7)) << 3);   // kk=1: chunks 4..7

  // prologue: tiles 0 -> buf0, 1 -> buf1; wait tile0 (leave tile1's 8 in flight)
  STAGE(0, 0);
  STAGE(64, 8192);
  asm volatile("s_waitcnt vmcnt(8)" ::: "memory");
  block_bar();

  for (int t = 0; t < NKT; ++t) {
    const int bsel = (t & 1) << 13;                  // 0 / 8192
#pragma unroll
    for (int kk = 0; kk < 2; ++kk) {
      const int sw = kk ? sw1 : sw0;
      bf16x8 bfrag[4];
#pragma unroll
      for (int j = 0; j < 4; ++j)
        bfrag[j] = *(const bf16x8*)&smem[bro + bsel + j * 1024 + sw];
#pragma unroll
      for (int i = 0; i < 4; ++i) {
        bf16x8 ai = *(const bf16x8*)&smem[aro + bsel + i * 1024 + sw];
#pragma unroll
        for (int j = 0; j < 4; ++j)
          acc[i][j] = __builtin_amdgcn_mfma_f32_16x16x32_bf16(ai, bfrag[j], acc[i][j], 0, 0, 0);
      }
    }
    asm volatile("s_waitcnt lgkmcnt(0)" ::: "memory");
    block_bar();                      // all waves done reading buf[t&1]
    if (t + 2 < NKT) {
      STAGE((t + 2) << 6, bsel);      // refill the buffer just consumed
      asm volatile("s_waitcnt vmcnt(8)" ::: "memory");   // tile t+1 landed
      block_bar();
    } else if (t + 1 < NKT) {
      asm volatile("s_waitcnt vmcnt(0)" ::: "memory");   // final prefetch drain
      block_bar();
    }
  }
#undef STAGE

  // ---- epilogue: per-fragment store (C or transposed-V path) ----
#pragma unroll
  for (int i = 0; i < 4; ++i) {
    const int rowb = mBase + (wm << 6) + (i << 4) + (quad << 2);
#pragma unroll
    for (int j = 0; j < 4; ++j) {
      const int colb = nBase + (wn << 6) + (j << 4);
      const int col  = colb + l16;
      if (colb < vcol0) {
#pragma unroll
        for (int r = 0; r < 4; ++r)
          store_elem(C, (size_t)(rowb + r) * N + col, acc[i][j][r]);
      } else {
        const int vcol = col - vcol0;
        const int bb = rowb >> 11;
        const int t  = rowb & 2047;
        uint2 pw;
        pw.x = bf16rne(acc[i][j][0]) | (bf16rne(acc[i][j][1]) << 16);
        pw.y = bf16rne(acc[i][j][2]) | (bf16rne(acc[i][j][3]) << 16);
        *(uint2*)(vt + (((size_t)(bb << 9) + vcol) << 11) + t) = pw;
      }
    }
  }
}

// ---- RoPE in-place on K columns only (q is roped in-register inside attn) ----
__global__ void rope_k(ushort* __restrict__ qkv, const float* __restrict__ fc,
                       const float* __restrict__ fs) {
  int idx  = blockIdx.x * 256 + threadIdx.x;   // exactly B*T*4*64 threads
  int d2   = idx & 63;
  int rest = idx >> 6;
  int hh   = rest & 3;                          // kv head 0..3
  int bt   = rest >> 2;
  int t    = bt & (T_SEQ - 1);
  float c = fc[(t << 6) + d2];
  float s = fs[(t << 6) + d2];
  uint* p = (uint*)(qkv + (size_t)bt * QKV_W + 2048 + (hh << 7) + (d2 << 1));
  uint w = *p;
  float e = bflo(w), o = bfhi(w);
  *p = bf16rne(e * c - o * s) | (bf16rne(e * s + o * c) << 16);
}

// ---- MFMA flash attention: Q-tile 128, key tile 64, EIGHT waves (512 thr) ----
// Grid 256 blocks (1/CU), blocks paired over Q-tiles {x, 15-x}: 34 chunks each.
// Wave-private P + dbuf direct global_load_lds staging -> ONE barrier per chunk.
// NEW (r8): Q-RoPE + QSCALE applied IN-REGISTER at qf load (pairs are in-lane
// since fragments hold 8 consecutive d elements) -- once per Q-tile, no shfl.
__global__ __launch_bounds__(512, 2) void attn_mfma(const ushort* __restrict__ qkv,
                                                    const ushort* __restrict__ vtg,
                                                    ushort* __restrict__ y,
                                                    const float* __restrict__ fc,
                                                    const float* __restrict__ fs) {
  __shared__ ushort smem[51456];          // 102912 B
  ushort* sP = smem + 32768;
  float*  sOf = (float*)smem;
  ushort* sO  = smem + 33792;
  float*  sLf = (float*)(smem + 51200);

  const int tid  = threadIdx.x;
  const int wave = tid >> 6, lane = tid & 63;
  const int quad = lane >> 4, l16 = lane & 15;
  const int w_s = wave & 1;               // s-block owner (QK rows + PV k-slice)
  const int w_t = wave >> 1;              // t-block (0..3)
  const int h = blockIdx.y, b = blockIdx.z, kh = h >> 2;
  const size_t bT = (size_t)b * T_SEQ;

  union { uint4 u; bf16x8 v; } ones_u;
  ones_u.u = make_uint4(0x3F803F80u, 0x3F803F80u, 0x3F803F80u, 0x3F803F80u);
  const bf16x8 onesf = ones_u.v;

  const int kr  = tid >> 4;
  const int kc8 = tid & 15;
  const ushort* gK = qkv + (bT + kr) * QKV_W + 2048 + kh * HD + ((kc8 ^ (kr & 7)) << 3);
  const int vd  = tid >> 3;
  const int vsc = tid & 7;
  const ushort* gV = vtg + (((size_t)(b << 9) + (kh << 7) + vd) << 11) + ((vsc ^ (vd & 7)) << 3);

#define STAGE_ATTN(cn, bo_)                                                            \
  do {                                                                                 \
    _Pragma("unroll")                                                                  \
    for (int it_ = 0; it_ < 2; ++it_)                                                  \
      __builtin_amdgcn_global_load_lds(                                                \
          (const __attribute__((address_space(1))) void*)(gK + ((size_t)(cn) * 64 + it_ * 32) * QKV_W), \
          (__attribute__((address_space(3))) void*)(smem + (bo_) + (wave << 9) + it_ * 4096), 16, 0, 0); \
    _Pragma("unroll")                                                                  \
    for (int it_ = 0; it_ < 2; ++it_)                                                  \
      __builtin_amdgcn_global_load_lds(                                                \
          (const __attribute__((address_space(1))) void*)(gV + ((size_t)it_ << 17) + (cn) * 64), \
          (__attribute__((address_space(3))) void*)(smem + 16384 + (bo_) + (wave << 9) + it_ * 4096), 16, 0, 0); \
  } while (0)

  for (int half = 0; half < 2; ++half) {
    const int xt = half ? (15 - (int)blockIdx.x) : (int)blockIdx.x;
    const int t0 = xt << 7;
    const int sblk = w_s << 5, tblk = w_t << 5;

    // Q fragments: load raw q, apply RoPE + QSCALE in-register (in-lane pairs)
    bf16x8 qf[2][4];
#pragma unroll
    for (int tt = 0; tt < 2; ++tt) {
      const int trow = t0 + tblk + tt * 16 + l16;
      const float* fcr = fc + (trow << 6);
      const float* fsr = fs + (trow << 6);
#pragma unroll
      for (int kk = 0; kk < 4; ++kk) {
        union { uint4 u; bf16x8 v; } qa;
        qa.u = *(const uint4*)(qkv + (bT + trow) * QKV_W + h * HD + kk * 32 + quad * 8);
        const int d2b = kk * 16 + quad * 4;
        uint* wp = (uint*)&qa.u;
#pragma unroll
        for (int m = 0; m < 4; ++m) {
          float c = fcr[d2b + m], s = fsr[d2b + m];
          float e = bflo(wp[m]), o = bfhi(wp[m]);
          float oe = (e * c - o * s) * QSCALE;
          float oo = (e * s + o * c) * QSCALE;
          wp[m] = bf16rne(oe) | (bf16rne(oo) << 16);
        }
        qf[tt][kk] = qa.v;
      }
    }

    floatx4 oacc[2][8];     // t-tile (2) x full d (8 x 16)
    floatx4 lacc[2];
#pragma unroll
    for (int tt = 0; tt < 2; ++tt) {
#pragma unroll
      for (int r = 0; r < 4; ++r) lacc[tt][r] = 0.f;
#pragma unroll
      for (int dt = 0; dt < 8; ++dt)
#pragma unroll
        for (int r = 0; r < 4; ++r) oacc[tt][dt][r] = 0.f;
    }

    const int nch = (t0 >> 6) + 2;

    STAGE_ATTN(0, 0);       // prologue: chunk 0 -> buf0 (drained by first sync)

    for (int ch = 0; ch < nch; ++ch) {
      __syncthreads();      // buf[ch&1] staged (vmcnt drained); prev reads done
      if (ch + 1 < nch) STAGE_ATTN(ch + 1, ((ch + 1) & 1) << 13);
      const int bo = (ch & 1) << 13;        // 0 / 8192
      const int s0 = ch << 6;

      const bool fullmask = (s0 + sblk) > (t0 + tblk + 31);
      if (!fullmask) {
        floatx4 accS[2][2];
#pragma unroll
        for (int st = 0; st < 2; ++st)
#pragma unroll
          for (int tt = 0; tt < 2; ++tt)
#pragma unroll
            for (int r = 0; r < 4; ++r) accS[st][tt][r] = 0.f;

#pragma unroll
        for (int kk = 0; kk < 4; ++kk) {
          bf16x8 kf0 = *(const bf16x8*)(smem + bo + (sblk + l16) * 128 +
                                        ((((kk << 2) + quad) ^ (l16 & 7)) << 3));
          bf16x8 kf1 = *(const bf16x8*)(smem + bo + (sblk + 16 + l16) * 128 +
                                        ((((kk << 2) + quad) ^ (l16 & 7)) << 3));
#pragma unroll
          for (int tt = 0; tt < 2; ++tt)
            accS[0][tt] = __builtin_amdgcn_mfma_f32_16x16x32_bf16(kf0, qf[tt][kk], accS[0][tt], 0, 0, 0);
#pragma unroll
          for (int tt = 0; tt < 2; ++tt)
            accS[1][tt] = __builtin_amdgcn_mfma_f32_16x16x32_bf16(kf1, qf[tt][kk], accS[1][tt], 0, 0, 0);
        }

        const bool diag = (s0 + sblk + 31) > (t0 + tblk);
#pragma unroll
        for (int st = 0; st < 2; ++st)
#pragma unroll
          for (int tt = 0; tt < 2; ++tt) {
            float p[4];
            if (diag) {
              const int sg = s0 + sblk + st * 16 + quad * 4;
              const int tg = t0 + tblk + tt * 16 + l16;
#pragma unroll
              for (int r = 0; r < 4; ++r)
                p[r] = (sg + r <= tg) ? EXP2F(accS[st][tt][r]) : 0.f;
            } else {
#pragma unroll
              for (int r = 0; r < 4; ++r) p[r] = EXP2F(accS[st][tt][r]);
            }
            uint2 pw;   // truncating bf16 pack (bias cancels in normalization)
            pw.x = (__float_as_uint(p[0]) >> 16) | (__float_as_uint(p[1]) & 0xFFFF0000u);
            pw.y = (__float_as_uint(p[2]) >> 16) | (__float_as_uint(p[3]) & 0xFFFF0000u);
            *(uint2*)(sP + (tblk + tt * 16 + l16) * 72 + sblk + st * 16 + quad * 4) = pw;
          }
        // no barrier: P is wave-private

        bf16x8 pf[2];
#pragma unroll
        for (int tt = 0; tt < 2; ++tt) {
          pf[tt] = *(const bf16x8*)(sP + (tblk + tt * 16 + l16) * 72 + sblk + (quad << 3));
          lacc[tt] = __builtin_amdgcn_mfma_f32_16x16x32_bf16(pf[tt], onesf, lacc[tt], 0, 0, 0);
        }
#pragma unroll
        for (int dt = 0; dt < 8; ++dt) {
          bf16x8 vf = *(const bf16x8*)(smem + 16384 + bo + (dt * 16 + l16) * 64 +
                                       ((((w_s << 2) + quad) ^ (l16 & 7)) << 3));
#pragma unroll
          for (int tt = 0; tt < 2; ++tt)
            oacc[tt][dt] = __builtin_amdgcn_mfma_f32_16x16x32_bf16(pf[tt], vf, oacc[tt][dt], 0, 0, 0);
        }
      }
    }

    // ---- epilogue: combine w_s partials, normalize, coalesced store ----
    __syncthreads();
    if (w_s == 0) {
#pragma unroll
      for (int tt = 0; tt < 2; ++tt) {
#pragma unroll
        for (int dt = 0; dt < 8; ++dt)
#pragma unroll
          for (int r = 0; r < 4; ++r)
            sOf[(tblk + tt * 16 + quad * 4 + r) * 132 + dt * 16 + l16] = oacc[tt][dt][r];
        if (l16 == 0) {
#pragma unroll
          for (int r = 0; r < 4; ++r)
            sLf[tblk + tt * 16 + quad * 4 + r] = lacc[tt][r];
        }
      }
    }
    __syncthreads();
    if (w_s == 1) {
#pragma unroll
      for (int tt = 0; tt < 2; ++tt) {
        float linv[4];
#pragma unroll
        for (int r = 0; r < 4; ++r)
          linv[r] = 1.0f / (sLf[tblk + tt * 16 + quad * 4 + r] + lacc[tt][r]);
#pragma unroll
        for (int dt = 0; dt < 8; ++dt)
#pragma unroll
          for (int r = 0; r < 4; ++r) {
            float v = (sOf[(tblk + tt * 16 + quad * 4 + r) * 132 + dt * 16 + l16] +
                       oacc[tt][dt][r]) * linv[r];
            sO[(tblk + tt * 16 + quad * 4 + r) * 136 + dt * 16 + l16] = (ushort)bf16rne(v);
          }
      }
    }
    __syncthreads();
#pragma unroll
    for (int it = 0; it < 4; ++it) {
      int idx = it * 512 + tid;                  // 0..2047 = 128 rows x 16 chunks
      int rr = idx >> 4, c8 = idx & 15;
      *(uint4*)(y + (bT + t0 + rr) * CDIM + h * HD + c8 * 8) =
          *(const uint4*)(sO + rr * 136 + c8 * 8);
    }
  }
#undef STAGE_ATTN
}

extern "C" void kernel_launch(void* const* d_in, const int* in_sizes, int n_in,
                              void* d_out, int out_size, void* d_ws, size_t ws_size,
                              hipStream_t stream) {
  const float* x    = (const float*)d_in[0];
  const float* fcos = (const float*)d_in[1];
  const float* fsin = (const float*)d_in[2];
  const float* wq   = (const float*)d_in[3];
  const float* wk   = (const float*)d_in[4];
  const float* wv   = (const float*)d_in[5];
  const float* wo   = (const float*)d_in[6];
  float* out = (float*)d_out;

  // workspace carve (bf16 elems); yb aliases xb (xb dead after gemm1)
  ushort* ws    = (ushort*)d_ws;
  ushort* xb    = ws;                          // 4096*2048 = 8,388,608
  ushort* yb    = ws;                          // alias of xb
  ushort* wqkvb = ws    + 8388608;             // 3072*2048 = 6,291,456
  ushort* wob   = wqkvb + 6291456;             // 2048*2048 = 4,194,304
  ushort* qkv   = wob   + 4194304;             // 4096*3072 = 12,582,912 (v cols unused)
  ushort* vtg   = qkv   + 12582912;            // 2*512*2048 = 2,097,152

  // 1) single merged fp32 -> bf16 cast (xb | wqkvb(q,k,v) | wob contiguous)
  cast_all<<<36864, 256, 0, stream>>>(x, wq, wk, wv, wo, (uint*)ws);

  // 2) qkv = xb @ Wqkv^T (raw q/k, no rope); V cols (>=2560) transposed to vtg
  gemm_bt<ushort><<<dim3(QKV_W / 128, MROWS / 128), 256, 0, stream>>>(
      xb, wqkvb, qkv, MROWS, QKV_W, CDIM, 2560, vtg);

  // 3) RoPE in place on K only (q is roped in-register inside attn)
  rope_k<<<4096, 256, 0, stream>>>(qkv, fcos, fsin);

  // 4) MFMA causal GQA attention (with in-register Q-RoPE+QSCALE) -> yb
  attn_mfma<<<dim3(8, NHEAD, NB), 512, 0, stream>>>(qkv, vtg, yb, fcos, fsin);

  // 5) out = yb @ wo^T (fp32 out)
  gemm_bt<float><<<dim3(CDIM / 128, MROWS / 128), 256, 0, stream>>>(
      yb, wob, out, MROWS, CDIM, CDIM, 1 << 30, nullptr);
}